// Round 11
// baseline (1262.754 us; speedup 1.0000x reference)
//
#include <hip/hip_runtime.h>
#include <math.h>

#define LMAXS 1024
#define NB 8
#define DIM 512
#define HEADS 8
#define DH 64
#define DEPTH 6
#define MLP 2048
#define NC 1000
#define PDIM 768
#define MPACK 5376   // 5360 valid rows padded to 42*128
#define MVALID 5360
#define QSCALE 0.18033688f   // 0.125 * log2(e), folded into Q

typedef __attribute__((ext_vector_type(8))) short short8;
typedef __attribute__((ext_vector_type(4))) float floatx4;
typedef unsigned short ushort;

__constant__ int c_w[8]   = {32,24,32,24,28,32,16,20};
__constant__ int c_L[8]   = {1024,768,896,576,560,512,384,640};
__constant__ int c_off[9] = {0,1024,1792,2688,3264,3824,4336,4720,5360};

__device__ __forceinline__ int row2img(int r) {
  int b = 0;
  #pragma unroll
  for (int i = 1; i < 8; ++i) if (r >= c_off[i]) b = i;
  return b;
}

__device__ __forceinline__ ushort f2bf(float x) {
  unsigned int u = __float_as_uint(x);
  u += 0x7fff + ((u >> 16) & 1);          // RNE
  return (ushort)(u >> 16);
}

#define GLOAD_LDS16(gp, lp) \
  __builtin_amdgcn_global_load_lds((const __attribute__((address_space(1))) void*)(gp), \
                                   (__attribute__((address_space(3))) void*)(lp), 16, 0, 0)

__device__ __forceinline__ void reduce2_256(float& s, float& s2, float* red) {
  #pragma unroll
  for (int off = 32; off; off >>= 1) {
    s  += __shfl_xor(s, off);
    s2 += __shfl_xor(s2, off);
  }
  int wv = threadIdx.x >> 6;
  if ((threadIdx.x & 63) == 0) { red[wv*2] = s; red[wv*2+1] = s2; }
  __syncthreads();
  s  = red[0] + red[2] + red[4] + red[6];
  s2 = red[1] + red[3] + red[5] + red[7];
  __syncthreads();
}

// ---- single fused weight conversion fp32 -> bf16 (all weights, 4 elems/thread) ----
__global__ __launch_bounds__(256) void cvt_all_k(
    const float* __restrict__ wq, const float* __restrict__ wk, const float* __restrict__ wv,
    const float* __restrict__ wo, const float* __restrict__ w1, const float* __restrict__ w2,
    const float* __restrict__ pew, const float* __restrict__ pwk, const float* __restrict__ pwv,
    ushort* __restrict__ WQKV, ushort* __restrict__ WO, ushort* __restrict__ W1,
    ushort* __restrict__ W2, ushort* __restrict__ PEW, ushort* __restrict__ PKV) {
  const long N0 = 4718592L;            // 6*1536*512 (QKV interleave)
  const long N1 = N0 + 1572864L;       // wo
  const long N2 = N1 + 6291456L;       // ff_w1
  const long N3 = N2 + 6291456L;       // ff_w2
  const long N4 = N3 + 393216L;        // pe_w
  const long N5 = N4 + 524288L;        // pool k/v stack
  long e = ((long)blockIdx.x*256 + threadIdx.x) * 4;
  if (e >= N5) return;
  const float* src; ushort* dst;
  if (e < N0) {
    long i = e;
    int l = (int)(i / (1536L*512)); int r = (int)((i/512) % 1536); int k = (int)(i & 511);
    const float* s = (r < 512) ? wq : (r < 1024) ? wk : wv;
    int rr = r & 511;
    src = s + (size_t)l*DIM*DIM + (size_t)rr*DIM + k; dst = WQKV + i;
  } else if (e < N1) { long o = e-N0; src = wo  + o; dst = WO  + o; }
  else if (e < N2)   { long o = e-N1; src = w1  + o; dst = W1  + o; }
  else if (e < N3)   { long o = e-N2; src = w2  + o; dst = W2  + o; }
  else if (e < N4)   { long o = e-N3; src = pew + o; dst = PEW + o; }
  else {
    long i = e-N4; int r = (int)(i >> 9); int k = (int)(i & 511);
    src = (r < 512) ? (pwk + (size_t)r*DIM + k) : (pwv + (size_t)(r-512)*DIM + k);
    dst = PKV + i;
  }
  float4 v = *(const float4*)src;
  ushort4 o4; o4.x=f2bf(v.x); o4.y=f2bf(v.y); o4.z=f2bf(v.z); o4.w=f2bf(v.w);
  *(ushort4*)dst = o4;
}

// ---- patchify + LN(768) -> bf16 packed tokens ----
__global__ __launch_bounds__(256) void pack_ln1_k(
    const float* __restrict__ images, const float* __restrict__ g,
    const float* __restrict__ bb, ushort* __restrict__ tok) {
  int r = blockIdx.x;
  ushort* out = tok + (size_t)r * PDIM;
  if (r >= MVALID) {
    for (int i = threadIdx.x; i < PDIM; i += 256) out[i] = 0;
    return;
  }
  int b = row2img(r), l = r - c_off[b];
  int wgrid = c_w[b];
  __shared__ float vals[PDIM];
  __shared__ float red[8];
  int hp = l / wgrid, wp = l % wgrid;
  const float* base = images + (size_t)b*3*512*512 + (size_t)hp*16*512 + wp*16;
  float s = 0.f, s2 = 0.f;
  for (int i = threadIdx.x; i < PDIM; i += 256) {
    int c = i >> 8, rr = (i >> 4) & 15, cc = i & 15;
    float v = base[(size_t)c*512*512 + rr*512 + cc];
    vals[i] = v; s += v; s2 += v*v;
  }
  reduce2_256(s, s2, red);
  float mu = s * (1.f/PDIM);
  float rs = rsqrtf(fmaxf(s2*(1.f/PDIM) - mu*mu, 0.f) + 1e-5f);
  for (int i = threadIdx.x; i < PDIM; i += 256)
    out[i] = f2bf((vals[i]-mu)*rs*g[i] + bb[i]);
}

// ---- generic bf16 MFMA GEMM, tile TM x TN (wave tile WM x WN), BK=64, swizzled async staging ----
// OUT: 0 = f32 store, 1 = f32 += (residual accumulate), 2 = bf16 store. ACT: 1 = exact gelu.
template<int TM, int TN, int WM, int WN, int ACT, int OUT>
__global__ __launch_bounds__(256) void gemm_t(
    const ushort* __restrict__ A, const ushort* __restrict__ W,
    const float* __restrict__ bias, void* __restrict__ Cv,
    int M, int N, int K) {
  constexpr int WAVES_N = TN / WN;
  constexpr int FM = WM / 16, FN = WN / 16;
  constexpr int NA = TM / 32, NW = TN / 32;
  __shared__ ushort As[TM*64];
  __shared__ ushort Ws[TN*64];
  int tid = threadIdx.x;
  int row0 = blockIdx.y*TM, col0 = blockIdx.x*TN;
  int lane = tid & 63, l15 = lane & 15, quad = lane >> 4;
  int wv = tid >> 6;
  int wm = wv / WAVES_N, wn = wv % WAVES_N;
  int sw = l15 & 7;
  int segA = (quad ^ sw) * 8, segB = segA ^ 32;
  const ushort *Ap[NA], *Wp[NW];
  #pragma unroll
  for (int j = 0; j < NA; ++j) {
    int blk = j*256 + tid;
    int r = blk >> 3, s = ((blk & 7) ^ (r & 7)) * 8;
    Ap[j] = A + (size_t)(row0 + r)*K + s;
  }
  #pragma unroll
  for (int j = 0; j < NW; ++j) {
    int blk = j*256 + tid;
    int r = blk >> 3, s = ((blk & 7) ^ (r & 7)) * 8;
    Wp[j] = W + (size_t)(col0 + r)*K + s;
  }
  floatx4 acc[FM][FN] = {};
  for (int k0 = 0; k0 < K; k0 += 64) {
    __syncthreads();
    #pragma unroll
    for (int j = 0; j < NA; ++j) GLOAD_LDS16(Ap[j] + k0, &As[(j*256+tid)*8]);
    #pragma unroll
    for (int j = 0; j < NW; ++j) GLOAD_LDS16(Wp[j] + k0, &Ws[(j*256+tid)*8]);
    __syncthreads();
    #pragma unroll
    for (int w = 0; w < 2; ++w) {
      int sg = w ? segB : segA;
      short8 af[FM], bf[FN];
      #pragma unroll
      for (int i = 0; i < FM; ++i) af[i] = *(const short8*)&As[(wm*WM + i*16 + l15)*64 + sg];
      #pragma unroll
      for (int j = 0; j < FN; ++j) bf[j] = *(const short8*)&Ws[(wn*WN + j*16 + l15)*64 + sg];
      #pragma unroll
      for (int i = 0; i < FM; ++i)
        #pragma unroll
        for (int j = 0; j < FN; ++j)
          acc[i][j] = __builtin_amdgcn_mfma_f32_16x16x32_bf16(af[i], bf[j], acc[i][j], 0, 0, 0);
    }
  }
  int rb = row0 + wm*WM + quad*4;
  int cb = col0 + wn*WN + l15;
  #pragma unroll
  for (int j = 0; j < FN; ++j) {
    int cc = cb + j*16;
    float bsum = bias ? bias[cc] : 0.f;
    #pragma unroll
    for (int i = 0; i < FM; ++i) {
      int rr = rb + i*16;
      #pragma unroll
      for (int reg = 0; reg < 4; ++reg) {
        float v = acc[i][j][reg] + bsum;
        if (ACT == 1) v = 0.5f*v*(1.f + erff(v*0.70710678118654752f));
        size_t idx = (size_t)(rr + reg)*N + cc;
        if (OUT == 0)      ((float*)Cv)[idx] = v;
        else if (OUT == 1) ((float*)Cv)[idx] += v;
        else               ((ushort*)Cv)[idx] = f2bf(v);
      }
    }
  }
}

// ---- QKV / pool-KV GEMM with fused per-head LN; V written DIRECTLY TRANSPOSED ----
// POOL=0: N=1536 -> Qh/Kh bf16 [b,h,l,64] (LN, Q scaled), V -> VhT [b,h,64,LMAX]
//         via scalar 2B stores (a wave covers 64 consecutive l per dh row, L2 merges
//         into full lines). Tail l>=Lb never written: 0xAA poison decodes to a FINITE
//         bf16, and masked P=0 makes its PV contribution exactly 0.
// POOL=1: N=1024 -> KV fp32 [row][1024] (LN on K cols<512).
template<int POOL>
__global__ __launch_bounds__(256) void gemm_qkv_k(
    const ushort* __restrict__ A, const ushort* __restrict__ W,
    const float* __restrict__ gq, const float* __restrict__ gk,
    ushort* __restrict__ Qh, ushort* __restrict__ Kh, ushort* __restrict__ VhT,
    float* __restrict__ KV, int N) {
  const int K = DIM;
  __shared__ ushort As[128*64];
  __shared__ ushort Ws[128*64];
  int tid = threadIdx.x;
  int row0 = blockIdx.y*128, col0 = blockIdx.x*128;
  int lane = tid & 63, l15 = lane & 15, quad = lane >> 4;
  int wv = tid >> 6, wm = wv >> 1, wn = wv & 1;
  int sw = l15 & 7;
  int segA = (quad ^ sw) * 8, segB = segA ^ 32;
  const ushort *Ap[4], *Wp[4];
  #pragma unroll
  for (int j = 0; j < 4; ++j) {
    int blk = j*256 + tid;
    int r = blk >> 3, s = ((blk & 7) ^ (r & 7)) * 8;
    Ap[j] = A + (size_t)(row0 + r)*K + s;
    Wp[j] = W + (size_t)(col0 + r)*K + s;
  }
  floatx4 acc[4][4] = {};
  for (int k0 = 0; k0 < K; k0 += 64) {
    __syncthreads();
    #pragma unroll
    for (int j = 0; j < 4; ++j) {
      GLOAD_LDS16(Ap[j] + k0, &As[(j*256+tid)*8]);
      GLOAD_LDS16(Wp[j] + k0, &Ws[(j*256+tid)*8]);
    }
    __syncthreads();
    #pragma unroll
    for (int w = 0; w < 2; ++w) {
      int sg = w ? segB : segA;
      short8 af[4], bf[4];
      #pragma unroll
      for (int i = 0; i < 4; ++i) af[i] = *(const short8*)&As[(wm*64 + i*16 + l15)*64 + sg];
      #pragma unroll
      for (int j = 0; j < 4; ++j) bf[j] = *(const short8*)&Ws[(wn*64 + j*16 + l15)*64 + sg];
      #pragma unroll
      for (int i = 0; i < 4; ++i)
        #pragma unroll
        for (int j = 0; j < 4; ++j)
          acc[i][j] = __builtin_amdgcn_mfma_f32_16x16x32_bf16(af[i], bf[j], acc[i][j], 0, 0, 0);
    }
  }
  int unit = (col0 >> 6) + wn;
  bool needln = POOL ? (unit < 8) : (unit < 16);
  const float* gain = POOL ? gq : (unit < 8 ? gq : gk);
  #pragma unroll
  for (int i = 0; i < 4; ++i) {
    float s[4] = {0,0,0,0}, s2[4] = {0,0,0,0};
    if (needln) {
      #pragma unroll
      for (int j = 0; j < 4; ++j)
        #pragma unroll
        for (int reg = 0; reg < 4; ++reg) {
          float v = acc[i][j][reg];
          s[reg] += v; s2[reg] += v*v;
        }
      #pragma unroll
      for (int reg = 0; reg < 4; ++reg)
        #pragma unroll
        for (int off = 1; off < 16; off <<= 1) {
          s[reg]  += __shfl_xor(s[reg],  off);
          s2[reg] += __shfl_xor(s2[reg], off);
        }
    }
    #pragma unroll
    for (int reg = 0; reg < 4; ++reg) {
      int r = row0 + wm*64 + i*16 + quad*4 + reg;
      if (r >= MVALID) continue;
      float mu = s[reg]*(1.f/64.f);
      float rs = rsqrtf(fmaxf(s2[reg]*(1.f/64.f) - mu*mu, 0.f) + 1e-5f);
      int b = row2img(r), l = r - c_off[b];
      #pragma unroll
      for (int j = 0; j < 4; ++j) {
        int dh = j*16 + l15;
        float v = acc[i][j][reg];
        if (needln) v = (v - mu)*rs*gain[dh];
        if (POOL) {
          KV[(size_t)r*1024 + unit*64 + dh] = v;
        } else {
          int h = unit & 7;
          if (unit < 8) {
            Qh[((size_t)(b*8+h)*LMAXS + l)*64 + dh] = f2bf(v * QSCALE);
          } else if (unit < 16) {
            Kh[((size_t)(b*8+h)*LMAXS + l)*64 + dh] = f2bf(v);
          } else {
            VhT[((size_t)(b*8+h)*64 + dh)*LMAXS + l] = f2bf(v);  // fused transpose
          }
        }
      }
    }
  }
}

// ---- row LayerNorm: fp32 T -> bf16 XN ----
__global__ __launch_bounds__(256) void row_ln_bf_k(
    const float* __restrict__ T, const float* __restrict__ g, ushort* __restrict__ Y) {
  __shared__ float red[8];
  size_t base = (size_t)blockIdx.x * DIM;
  float v0 = T[base + threadIdx.x], v1 = T[base + threadIdx.x + 256];
  float s = v0 + v1, s2 = v0*v0 + v1*v1;
  reduce2_256(s, s2, red);
  float mu = s*(1.f/DIM), rs = rsqrtf(fmaxf(s2*(1.f/DIM) - mu*mu, 0.f) + 1e-5f);
  Y[base + threadIdx.x]       = f2bf((v0-mu)*rs*g[threadIdx.x]);
  Y[base + threadIdx.x + 256] = f2bf((v1-mu)*rs*g[threadIdx.x + 256]);
}

// ---- LN2 + bias + pos embed, packed, in place on fp32 T ----
__global__ __launch_bounds__(256) void ln2_pos_k(
    float* __restrict__ T, const float* __restrict__ g, const float* __restrict__ bb,
    const float* __restrict__ ph, const float* __restrict__ pw) {
  int r = blockIdx.x;
  float* x = T + (size_t)r * DIM;
  if (r >= MVALID) {
    for (int i = threadIdx.x; i < DIM; i += 256) x[i] = 0.f;
    return;
  }
  int b = row2img(r), l = r - c_off[b];
  __shared__ float red[8];
  int wgrid = c_w[b];
  int hi = l / wgrid, wi = l % wgrid;
  float s=0.f, s2=0.f;
  for (int i = threadIdx.x; i < DIM; i += 256) { float v = x[i]; s+=v; s2+=v*v; }
  reduce2_256(s, s2, red);
  float mu = s*(1.f/DIM), rs = rsqrtf(fmaxf(s2*(1.f/DIM)-mu*mu, 0.f)+1e-5f);
  for (int i = threadIdx.x; i < DIM; i += 256)
    x[i] = (x[i]-mu)*rs*g[i] + bb[i] + ph[hi*DIM+i] + pw[wi*DIM+i];
}

// ---- flash-decoding attention, phase 1: per (bh, qtile, key-slice of 512) ----
// PART slice layout: 4160 floats = O[64q][64d] then l[64q].
__global__ __launch_bounds__(256) void attn_part_k(
    const ushort* __restrict__ Qh, const ushort* __restrict__ Kh,
    const ushort* __restrict__ VhT, float* __restrict__ PART) {
  int bh = blockIdx.x, b = bh >> 3;
  int Lb = c_L[b];
  int qt = blockIdx.y, z = blockIdx.z;
  if (qt*64 >= Lb || z*512 >= Lb) return;
  __shared__ ushort Ks[64*64];
  __shared__ ushort Vt[64*64];
  __shared__ ushort Pb[4][16][68];
  int tid = threadIdx.x, wv = tid >> 6, lane = tid & 63;
  int quad = lane >> 4, l15 = lane & 15;
  int sw = l15 & 7;
  int segA = (quad ^ sw) * 8, segB = segA ^ 32;
  int q0 = qt*64 + wv*16;
  bool active = q0 < Lb;
  const ushort* qhb = Qh + (size_t)bh * LMAXS * DH;
  const ushort* khb = Kh + (size_t)bh * LMAXS * DH;
  const ushort* vtb = VhT + (size_t)bh * DH * LMAXS;
  short8 aq0 = {}, aq1 = {};
  if (active) {
    const ushort* qp = qhb + (size_t)(q0 + l15) * DH;
    aq0 = *(const short8*)(qp + quad*8);
    aq1 = *(const short8*)(qp + 32 + quad*8);
  }
  int blk0 = tid, blk1 = tid + 256;
  int kr0 = blk0 >> 3, s0 = ((blk0 & 7) ^ (kr0 & 7)) * 8;
  int kr1 = blk1 >> 3, s1 = ((blk1 & 7) ^ (kr1 & 7)) * 8;
  const ushort* kg0 = khb + kr0*DH + s0;
  const ushort* kg1 = khb + kr1*DH + s1;
  const ushort* vg0 = vtb + (size_t)kr0*LMAXS + s0;
  const ushort* vg1 = vtb + (size_t)kr1*LMAXS + s1;
  int kbeg = z*512, kend = min(kbeg + 512, Lb);
  float lsum[4] = {0.f,0.f,0.f,0.f};
  floatx4 o[4] = {};
  for (int kc = kbeg; kc < kend; kc += 64) {
    __syncthreads();
    GLOAD_LDS16(kg0 + kc*DH, &Ks[blk0*8]);
    GLOAD_LDS16(kg1 + kc*DH, &Ks[blk1*8]);
    GLOAD_LDS16(vg0 + kc,    &Vt[blk0*8]);
    GLOAD_LDS16(vg1 + kc,    &Vt[blk1*8]);
    __syncthreads();
    if (!active) continue;
    bool tail = (kc + 64 > Lb);
    #pragma unroll
    for (int kb = 0; kb < 4; ++kb) {
      int krow = (kb*16 + l15) * 64;
      floatx4 s = {};
      s = __builtin_amdgcn_mfma_f32_16x16x32_bf16(aq0, *(const short8*)&Ks[krow + segA], s, 0,0,0);
      s = __builtin_amdgcn_mfma_f32_16x16x32_bf16(aq1, *(const short8*)&Ks[krow + segB], s, 0,0,0);
      #pragma unroll
      for (int reg = 0; reg < 4; ++reg) {
        float x = s[reg];
        if (tail && (kc + kb*16 + l15 >= Lb)) x = -1e9f;
        float p = __builtin_amdgcn_exp2f(x);
        lsum[reg] += p;
        Pb[wv][quad*4+reg][kb*16+l15] = f2bf(p);
      }
    }
    short8 a0 = *(const short8*)&Pb[wv][l15][quad*8];
    short8 a1 = *(const short8*)&Pb[wv][l15][32+quad*8];
    #pragma unroll
    for (int nb = 0; nb < 4; ++nb) {
      int vrow = (nb*16 + l15) * 64;
      o[nb] = __builtin_amdgcn_mfma_f32_16x16x32_bf16(a0, *(const short8*)&Vt[vrow + segA], o[nb], 0,0,0);
      o[nb] = __builtin_amdgcn_mfma_f32_16x16x32_bf16(a1, *(const short8*)&Vt[vrow + segB], o[nb], 0,0,0);
    }
  }
  if (active) {
    size_t sb = ((size_t)(bh*16 + qt)*2 + z) * 4160;
    #pragma unroll
    for (int reg = 0; reg < 4; ++reg) {
      float s = lsum[reg];
      s += __shfl_xor(s,1); s += __shfl_xor(s,2); s += __shfl_xor(s,4); s += __shfl_xor(s,8);
      if (l15 == 0) PART[sb + 4096 + wv*16 + quad*4 + reg] = s;
    }
    int rq = wv*16 + quad*4;
    #pragma unroll
    for (int nb = 0; nb < 4; ++nb)
      #pragma unroll
      for (int reg = 0; reg < 4; ++reg)
        PART[sb + (size_t)(rq + reg)*64 + nb*16 + l15] = o[nb][reg];
  }
}

// ---- flash-decoding attention, phase 2: combine slices, write bf16 ATTO ----
__global__ __launch_bounds__(256) void attn_comb_k(
    const float* __restrict__ PART, ushort* __restrict__ O) {
  int bh = blockIdx.x, b = bh >> 3, h = bh & 7;
  int Lb = c_L[b];
  int qt = blockIdx.y;
  if (qt*64 >= Lb) return;
  int nsl = (Lb + 511) >> 9;
  int t = threadIdx.x;
  int q = t >> 2, dj = (t & 3) * 16;
  int qq = qt*64 + q;
  if (qq >= Lb) return;
  size_t base = (size_t)(bh*16 + qt)*2*4160;
  float o[16] = {};
  float l = 0.f;
  for (int zz = 0; zz < nsl; ++zz) {
    const float* sp = PART + base + (size_t)zz*4160;
    #pragma unroll
    for (int i = 0; i < 16; i += 4) {
      float4 v = *(const float4*)&sp[q*64 + dj + i];
      o[i] += v.x; o[i+1] += v.y; o[i+2] += v.z; o[i+3] += v.w;
    }
    l += sp[4096 + q];
  }
  float inv = 1.f / l;
  short8 r0, r1;
  #pragma unroll
  for (int i = 0; i < 8; ++i) r0[i] = (short)f2bf(o[i]*inv);
  #pragma unroll
  for (int i = 0; i < 8; ++i) r1[i] = (short)f2bf(o[8+i]*inv);
  ushort* dst = O + (size_t)(c_off[b]+qq)*DIM + h*DH + dj;
  *(short8*)dst     = r0;
  *(short8*)(dst+8) = r1;
}

// ---- fused pool query prep: LN(pool_q) @ pool_wq^T then per-head LN, one block ----
__global__ __launch_bounds__(512) void pool_prep_k(
    const float* __restrict__ pq, const float* __restrict__ pln,
    const float* __restrict__ pwq, const float* __restrict__ pqn,
    float* __restrict__ qpool) {
  __shared__ float qln[DIM];
  __shared__ float red[16];
  int tid = threadIdx.x;
  float v = pq[tid];
  float s = v, s2 = v*v;
  #pragma unroll
  for (int off = 32; off; off >>= 1) { s += __shfl_xor(s, off); s2 += __shfl_xor(s2, off); }
  int wvv = tid >> 6;
  if ((tid & 63) == 0) { red[wvv*2] = s; red[wvv*2+1] = s2; }
  __syncthreads();
  s = 0.f; s2 = 0.f;
  #pragma unroll
  for (int i = 0; i < 8; ++i) { s += red[i*2]; s2 += red[i*2+1]; }
  float mu = s*(1.f/DIM), rs = rsqrtf(fmaxf(s2*(1.f/DIM)-mu*mu, 0.f)+1e-5f);
  qln[tid] = (v-mu)*rs*pln[tid];
  __syncthreads();
  const float4* wr = (const float4*)(pwq + (size_t)tid*DIM);
  float a = 0.f;
  #pragma unroll 8
  for (int k = 0; k < DIM/4; ++k) {
    float4 w4 = wr[k];
    float4 q4 = *(const float4*)&qln[k*4];
    a += w4.x*q4.x + w4.y*q4.y + w4.z*q4.z + w4.w*q4.w;
  }
  float hs = a, hs2 = a*a;
  #pragma unroll
  for (int off = 32; off; off >>= 1) { hs += __shfl_xor(hs, off); hs2 += __shfl_xor(hs2, off); }
  float hmu = hs*(1.f/64), hrs = rsqrtf(fmaxf(hs2*(1.f/64)-hmu*hmu, 0.f)+1e-5f);
  qpool[tid] = (a-hmu)*hrs*pqn[tid & 63];
}

// ---- pooling cross-attention, phase 1 ----
__global__ __launch_bounds__(256) void pool_attn_part_k(
    const float* __restrict__ qpool, const float* __restrict__ KV,
    float* __restrict__ PARTP) {
  __shared__ float qh[DH];
  __shared__ float ps[256];
  __shared__ float op[4][DH];
  __shared__ float red[8];
  int bh = blockIdx.x, c = blockIdx.y;
  int b = bh>>3, h = bh&7;
  int Lb = c_L[b];
  int tid = threadIdx.x;
  if (tid < DH) qh[tid] = qpool[h*DH + tid];
  __syncthreads();
  int kk = c*256 + tid;
  float p = 0.f;
  if (kk < Lb) {
    const float4* kp = (const float4*)(KV + (size_t)(c_off[b]+kk)*1024 + h*DH);
    float a = 0.f;
    #pragma unroll
    for (int dd=0; dd<16; ++dd) {
      float4 kv = kp[dd];
      a += kv.x*qh[dd*4] + kv.y*qh[dd*4+1] + kv.z*qh[dd*4+2] + kv.w*qh[dd*4+3];
    }
    p = __expf(a*0.125f);
  }
  ps[tid] = p;
  float s = p, s2 = 0.f;
  reduce2_256(s, s2, red);
  int wvv = tid >> 6, lane = tid & 63;
  float o = 0.f;
  int kb = c*256 + wvv*64;
  const float* vb = KV + (size_t)c_off[b]*1024 + 512 + h*DH + lane;
  for (int j = 0; j < 64; ++j) {
    int key = kb + j;
    if (key < Lb) o += ps[wvv*64+j] * vb[(size_t)key*1024];
  }
  op[wvv][lane] = o;
  __syncthreads();
  if (tid < DH)
    PARTP[((size_t)bh*4 + c)*66 + tid] = op[0][tid]+op[1][tid]+op[2][tid]+op[3][tid];
  if (tid == 64)
    PARTP[((size_t)bh*4 + c)*66 + 64] = s;
}

// ---- pooling cross-attention, phase 2 ----
__global__ __launch_bounds__(64) void pool_attn_comb_k(
    const float* __restrict__ PARTP, float* __restrict__ O) {
  int bh = blockIdx.x, b = bh>>3, h = bh&7, d = threadIdx.x;
  float o = 0.f, sum = 0.f;
  #pragma unroll
  for (int c = 0; c < 4; ++c) {
    o   += PARTP[((size_t)bh*4 + c)*66 + d];
    sum += PARTP[((size_t)bh*4 + c)*66 + 64];
  }
  O[(size_t)b*DIM + h*DH + d] = o / sum;
}

// ---- tiny projection, column-split ----
__global__ __launch_bounds__(256) void proj512_k(
    const float* __restrict__ X, const float* __restrict__ W, float* __restrict__ Y) {
  __shared__ float xr[DIM];
  int b = blockIdx.x, tid = threadIdx.x;
  for (int i=tid;i<DIM;i+=256) xr[i] = X[(size_t)b*DIM+i];
  __syncthreads();
  if (tid < 128) {
    int n = blockIdx.y*128 + tid;
    const float4* wr = (const float4*)(W + (size_t)n*DIM);
    float a=0.f;
    for (int k=0;k<DIM/4;++k) { float4 w4 = wr[k]; a += w4.x*xr[k*4]+w4.y*xr[k*4+1]+w4.z*xr[k*4+2]+w4.w*xr[k*4+3]; }
    Y[(size_t)b*DIM+n]=a;
  }
}

// ---- final LN + classifier head, column-split ----
__global__ __launch_bounds__(256) void head_out_k(
    const float* __restrict__ X, const float* __restrict__ g,
    const float* __restrict__ W, float* __restrict__ out) {
  __shared__ float xr[DIM];
  __shared__ float red[8];
  int b = blockIdx.x, tid = threadIdx.x;
  float s=0.f, s2=0.f;
  for (int i=tid;i<DIM;i+=256){ float v=X[(size_t)b*DIM+i]; s+=v; s2+=v*v; }
  reduce2_256(s, s2, red);
  float mu=s*(1.f/DIM), rs=rsqrtf(fmaxf(s2*(1.f/DIM)-mu*mu,0.f)+1e-5f);
  for (int i=tid;i<DIM;i+=256) xr[i]=(X[(size_t)b*DIM+i]-mu)*rs*g[i];
  __syncthreads();
  if (tid < 125) {
    int n = blockIdx.y*125 + tid;
    const float4* wr = (const float4*)(W + (size_t)n*DIM);
    float a=0.f;
    for (int k=0;k<DIM/4;++k){ float4 w4=wr[k]; a += w4.x*xr[k*4]+w4.y*xr[k*4+1]+w4.z*xr[k*4+2]+w4.w*xr[k*4+3]; }
    out[(size_t)b*NC+n]=a;
  }
}

extern "C" void kernel_launch(void* const* d_in, const int* in_sizes, int n_in,
                              void* d_out, int out_size, void* d_ws, size_t ws_size,
                              hipStream_t stream) {
  const float* images  = (const float*)d_in[0];
  const float* pe_ln1_w= (const float*)d_in[1];
  const float* pe_ln1_b= (const float*)d_in[2];
  const float* pe_w    = (const float*)d_in[3];
  const float* pe_b    = (const float*)d_in[4];
  const float* pe_ln2_w= (const float*)d_in[5];
  const float* pe_ln2_b= (const float*)d_in[6];
  const float* pos_h   = (const float*)d_in[7];
  const float* pos_w   = (const float*)d_in[8];
  const float* attn_ln = (const float*)d_in[9];
  const float* wq      = (const float*)d_in[10];
  const float* wk      = (const float*)d_in[11];
  const float* wvp     = (const float*)d_in[12];
  const float* qn      = (const float*)d_in[13];
  const float* kn      = (const float*)d_in[14];
  const float* wo      = (const float*)d_in[15];
  const float* ff_ln   = (const float*)d_in[16];
  const float* ff_w1   = (const float*)d_in[17];
  const float* ff_b1   = (const float*)d_in[18];
  const float* ff_w2   = (const float*)d_in[19];
  const float* ff_b2   = (const float*)d_in[20];
  const float* final_ln= (const float*)d_in[21];
  const float* pool_q  = (const float*)d_in[22];
  const float* pool_ln = (const float*)d_in[23];
  const float* pool_wq = (const float*)d_in[24];
  const float* pool_wk = (const float*)d_in[25];
  const float* pool_wv = (const float*)d_in[26];
  const float* pool_qn = (const float*)d_in[27];
  const float* pool_kn = (const float*)d_in[28];
  const float* pool_wo = (const float*)d_in[29];
  const float* head_ln = (const float*)d_in[30];
  const float* head_w  = (const float*)d_in[31];
  (void)ws_size; (void)in_sizes; (void)n_in; (void)out_size;

  char* p = (char*)d_ws;
  ushort* WQKVc = (ushort*)p; p += (size_t)6*1536*512*2;
  ushort* WOc   = (ushort*)p; p += (size_t)6*512*512*2;
  ushort* W1c   = (ushort*)p; p += (size_t)6*2048*512*2;
  ushort* W2c   = (ushort*)p; p += (size_t)6*512*2048*2;
  ushort* PEWc  = (ushort*)p; p += (size_t)512*768*2;
  ushort* PKVc  = (ushort*)p; p += (size_t)1024*512*2;
  float*  T     = (float*)p;  p += (size_t)MPACK*DIM*4;
  ushort* XN    = (ushort*)p; p += (size_t)MPACK*DIM*2;
  ushort* Qh    = (ushort*)p; p += (size_t)64*LMAXS*DH*2;
  ushort* Kh    = (ushort*)p; p += (size_t)64*LMAXS*DH*2;
  ushort* VhT   = (ushort*)p; p += (size_t)64*64*LMAXS*2;
  ushort* FFH   = (ushort*)p; p += (size_t)MPACK*MLP*2;   // TOK/ATTO alias inside
  ushort* TOK   = FFH;
  ushort* ATTO  = FFH;
  float*  PART  = (float*)p;  p += (size_t)64*16*2*4160*4; // 34.1 MB
  float*  KVb   = (float*)p;  p += (size_t)MPACK*1024*4;   // 22.0 MB
  float*  QPOOL = (float*)p;  p += DIM*4;
  float*  POOLO = (float*)p;  p += NB*DIM*4;
  float*  POOLED= (float*)p;  p += NB*DIM*4;
  float*  PARTP = (float*)p;  p += (size_t)64*4*66*4;

  // ---- fused weight conversion (single dispatch, same work every call) ----
  cvt_all_k<<<19328, 256, 0, stream>>>(wq, wk, wvp, wo, ff_w1, ff_w2, pe_w,
                                       pool_wk, pool_wv,
                                       WQKVc, WOc, W1c, W2c, PEWc, PKVc);

  // ---- patch embed (packed) ----
  pack_ln1_k<<<MPACK, 256, 0, stream>>>(images, pe_ln1_w, pe_ln1_b, TOK);
  gemm_t<64,128,64,32,0,0><<<dim3(4, MPACK/64), 256, 0, stream>>>(TOK, PEWc, pe_b, T, MPACK, DIM, PDIM);
  ln2_pos_k<<<MPACK, 256, 0, stream>>>(T, pe_ln2_w, pe_ln2_b, pos_h, pos_w);

  // ---- transformer layers ----
  for (int l = 0; l < DEPTH; ++l) {
    row_ln_bf_k<<<MPACK, 256, 0, stream>>>(T, attn_ln + l*DIM, XN);
    gemm_qkv_k<0><<<dim3(12, MPACK/128), 256, 0, stream>>>(
        XN, WQKVc + (size_t)l*1536*512, qn + l*DH, kn + l*DH, Qh, Kh, VhT, nullptr, 1536);
    attn_part_k<<<dim3(64, 16, 2), 256, 0, stream>>>(Qh, Kh, VhT, PART);
    attn_comb_k<<<dim3(64, 16), 256, 0, stream>>>(PART, ATTO);
    gemm_t<64,64,32,32,0,1><<<dim3(8, MPACK/64), 256, 0, stream>>>(ATTO, WOc + (size_t)l*512*512, nullptr, T, MPACK, DIM, DIM);
    row_ln_bf_k<<<MPACK, 256, 0, stream>>>(T, ff_ln + l*DIM, XN);
    gemm_t<64,128,64,32,1,2><<<dim3(16, MPACK/64), 256, 0, stream>>>(XN, W1c + (size_t)l*MLP*DIM, ff_b1 + l*MLP, FFH, MPACK, MLP, DIM);
    gemm_t<64,64,32,32,0,1><<<dim3(8, MPACK/64), 256, 0, stream>>>(FFH, W2c + (size_t)l*DIM*MLP, ff_b2 + l*DIM, T, MPACK, DIM, MLP);
  }

  // ---- pooling head ----
  row_ln_bf_k<<<MPACK, 256, 0, stream>>>(T, final_ln, XN);
  pool_prep_k<<<1, 512, 0, stream>>>(pool_q, pool_ln, pool_wq, pool_qn, QPOOL);
  gemm_qkv_k<1><<<dim3(8, MPACK/128), 256, 0, stream>>>(
      XN, PKVc, pool_kn, nullptr, nullptr, nullptr, nullptr, KVb, 1024);
  pool_attn_part_k<<<dim3(64, 4), 256, 0, stream>>>(QPOOL, KVb, PARTP);
  pool_attn_comb_k<<<64, 64, 0, stream>>>(PARTP, POOLO);
  proj512_k<<<dim3(8, 4), 256, 0, stream>>>(POOLO, pool_wo, POOLED);
  head_out_k<<<dim3(8, 8), 256, 0, stream>>>(POOLED, head_ln, head_w, (float*)d_out);
}

// Round 12
// 1178.578 us; speedup vs baseline: 1.0714x; 1.0714x over previous
//
#include <hip/hip_runtime.h>
#include <math.h>

#define LMAXS 1024
#define NB 8
#define DIM 512
#define HEADS 8
#define DH 64
#define DEPTH 6
#define MLP 2048
#define NC 1000
#define PDIM 768
#define MPACK 5376   // 5360 valid rows padded to 42*128
#define MVALID 5360
#define QSCALE 0.18033688f   // 0.125 * log2(e), folded into Q

typedef __attribute__((ext_vector_type(8))) short short8;
typedef __attribute__((ext_vector_type(4))) float floatx4;
typedef unsigned short ushort;

__constant__ int c_w[8]   = {32,24,32,24,28,32,16,20};
__constant__ int c_L[8]   = {1024,768,896,576,560,512,384,640};
__constant__ int c_off[9] = {0,1024,1792,2688,3264,3824,4336,4720,5360};

__device__ __forceinline__ int row2img(int r) {
  int b = 0;
  #pragma unroll
  for (int i = 1; i < 8; ++i) if (r >= c_off[i]) b = i;
  return b;
}

__device__ __forceinline__ ushort f2bf(float x) {
  unsigned int u = __float_as_uint(x);
  u += 0x7fff + ((u >> 16) & 1);          // RNE
  return (ushort)(u >> 16);
}

#define GLOAD_LDS16(gp, lp) \
  __builtin_amdgcn_global_load_lds((const __attribute__((address_space(1))) void*)(gp), \
                                   (__attribute__((address_space(3))) void*)(lp), 16, 0, 0)

__device__ __forceinline__ void reduce2_256(float& s, float& s2, float* red) {
  #pragma unroll
  for (int off = 32; off; off >>= 1) {
    s  += __shfl_xor(s, off);
    s2 += __shfl_xor(s2, off);
  }
  int wv = threadIdx.x >> 6;
  if ((threadIdx.x & 63) == 0) { red[wv*2] = s; red[wv*2+1] = s2; }
  __syncthreads();
  s  = red[0] + red[2] + red[4] + red[6];
  s2 = red[1] + red[3] + red[5] + red[7];
  __syncthreads();
}

// ---- single fused weight conversion fp32 -> bf16 (all weights, 4 elems/thread) ----
__global__ __launch_bounds__(256) void cvt_all_k(
    const float* __restrict__ wq, const float* __restrict__ wk, const float* __restrict__ wv,
    const float* __restrict__ wo, const float* __restrict__ w1, const float* __restrict__ w2,
    const float* __restrict__ pew, const float* __restrict__ pwk, const float* __restrict__ pwv,
    ushort* __restrict__ WQKV, ushort* __restrict__ WO, ushort* __restrict__ W1,
    ushort* __restrict__ W2, ushort* __restrict__ PEW, ushort* __restrict__ PKV) {
  const long N0 = 4718592L;            // 6*1536*512 (QKV interleave)
  const long N1 = N0 + 1572864L;       // wo
  const long N2 = N1 + 6291456L;       // ff_w1
  const long N3 = N2 + 6291456L;       // ff_w2
  const long N4 = N3 + 393216L;        // pe_w
  const long N5 = N4 + 524288L;        // pool k/v stack
  long e = ((long)blockIdx.x*256 + threadIdx.x) * 4;
  if (e >= N5) return;
  const float* src; ushort* dst;
  if (e < N0) {
    long i = e;
    int l = (int)(i / (1536L*512)); int r = (int)((i/512) % 1536); int k = (int)(i & 511);
    const float* s = (r < 512) ? wq : (r < 1024) ? wk : wv;
    int rr = r & 511;
    src = s + (size_t)l*DIM*DIM + (size_t)rr*DIM + k; dst = WQKV + i;
  } else if (e < N1) { long o = e-N0; src = wo  + o; dst = WO  + o; }
  else if (e < N2)   { long o = e-N1; src = w1  + o; dst = W1  + o; }
  else if (e < N3)   { long o = e-N2; src = w2  + o; dst = W2  + o; }
  else if (e < N4)   { long o = e-N3; src = pew + o; dst = PEW + o; }
  else {
    long i = e-N4; int r = (int)(i >> 9); int k = (int)(i & 511);
    src = (r < 512) ? (pwk + (size_t)r*DIM + k) : (pwv + (size_t)(r-512)*DIM + k);
    dst = PKV + i;
  }
  float4 v = *(const float4*)src;
  ushort4 o4; o4.x=f2bf(v.x); o4.y=f2bf(v.y); o4.z=f2bf(v.z); o4.w=f2bf(v.w);
  *(ushort4*)dst = o4;
}

// ---- patchify + LN(768) -> bf16 packed tokens ----
__global__ __launch_bounds__(256) void pack_ln1_k(
    const float* __restrict__ images, const float* __restrict__ g,
    const float* __restrict__ bb, ushort* __restrict__ tok) {
  int r = blockIdx.x;
  ushort* out = tok + (size_t)r * PDIM;
  if (r >= MVALID) {
    for (int i = threadIdx.x; i < PDIM; i += 256) out[i] = 0;
    return;
  }
  int b = row2img(r), l = r - c_off[b];
  int wgrid = c_w[b];
  __shared__ float vals[PDIM];
  __shared__ float red[8];
  int hp = l / wgrid, wp = l % wgrid;
  const float* base = images + (size_t)b*3*512*512 + (size_t)hp*16*512 + wp*16;
  float s = 0.f, s2 = 0.f;
  for (int i = threadIdx.x; i < PDIM; i += 256) {
    int c = i >> 8, rr = (i >> 4) & 15, cc = i & 15;
    float v = base[(size_t)c*512*512 + rr*512 + cc];
    vals[i] = v; s += v; s2 += v*v;
  }
  reduce2_256(s, s2, red);
  float mu = s * (1.f/PDIM);
  float rs = rsqrtf(fmaxf(s2*(1.f/PDIM) - mu*mu, 0.f) + 1e-5f);
  for (int i = threadIdx.x; i < PDIM; i += 256)
    out[i] = f2bf((vals[i]-mu)*rs*g[i] + bb[i]);
}

// ---- generic bf16 MFMA GEMM, tile TM x TN (wave tile WM x WN), BK=64, swizzled async staging ----
// OUT: 0 = f32 store, 1 = f32 += (residual accumulate), 2 = bf16 store. ACT: 1 = exact gelu.
template<int TM, int TN, int WM, int WN, int ACT, int OUT>
__global__ __launch_bounds__(256) void gemm_t(
    const ushort* __restrict__ A, const ushort* __restrict__ W,
    const float* __restrict__ bias, void* __restrict__ Cv,
    int M, int N, int K) {
  constexpr int WAVES_N = TN / WN;
  constexpr int FM = WM / 16, FN = WN / 16;
  constexpr int NA = TM / 32, NW = TN / 32;
  __shared__ ushort As[TM*64];
  __shared__ ushort Ws[TN*64];
  int tid = threadIdx.x;
  int row0 = blockIdx.y*TM, col0 = blockIdx.x*TN;
  int lane = tid & 63, l15 = lane & 15, quad = lane >> 4;
  int wv = tid >> 6;
  int wm = wv / WAVES_N, wn = wv % WAVES_N;
  int sw = l15 & 7;
  int segA = (quad ^ sw) * 8, segB = segA ^ 32;
  const ushort *Ap[NA], *Wp[NW];
  #pragma unroll
  for (int j = 0; j < NA; ++j) {
    int blk = j*256 + tid;
    int r = blk >> 3, s = ((blk & 7) ^ (r & 7)) * 8;
    Ap[j] = A + (size_t)(row0 + r)*K + s;
  }
  #pragma unroll
  for (int j = 0; j < NW; ++j) {
    int blk = j*256 + tid;
    int r = blk >> 3, s = ((blk & 7) ^ (r & 7)) * 8;
    Wp[j] = W + (size_t)(col0 + r)*K + s;
  }
  floatx4 acc[FM][FN] = {};
  for (int k0 = 0; k0 < K; k0 += 64) {
    __syncthreads();
    #pragma unroll
    for (int j = 0; j < NA; ++j) GLOAD_LDS16(Ap[j] + k0, &As[(j*256+tid)*8]);
    #pragma unroll
    for (int j = 0; j < NW; ++j) GLOAD_LDS16(Wp[j] + k0, &Ws[(j*256+tid)*8]);
    __syncthreads();
    #pragma unroll
    for (int w = 0; w < 2; ++w) {
      int sg = w ? segB : segA;
      short8 af[FM], bf[FN];
      #pragma unroll
      for (int i = 0; i < FM; ++i) af[i] = *(const short8*)&As[(wm*WM + i*16 + l15)*64 + sg];
      #pragma unroll
      for (int j = 0; j < FN; ++j) bf[j] = *(const short8*)&Ws[(wn*WN + j*16 + l15)*64 + sg];
      #pragma unroll
      for (int i = 0; i < FM; ++i)
        #pragma unroll
        for (int j = 0; j < FN; ++j)
          acc[i][j] = __builtin_amdgcn_mfma_f32_16x16x32_bf16(af[i], bf[j], acc[i][j], 0, 0, 0);
    }
  }
  int rb = row0 + wm*WM + quad*4;
  int cb = col0 + wn*WN + l15;
  #pragma unroll
  for (int j = 0; j < FN; ++j) {
    int cc = cb + j*16;
    float bsum = bias ? bias[cc] : 0.f;
    #pragma unroll
    for (int i = 0; i < FM; ++i) {
      int rr = rb + i*16;
      #pragma unroll
      for (int reg = 0; reg < 4; ++reg) {
        float v = acc[i][j][reg] + bsum;
        if (ACT == 1) v = 0.5f*v*(1.f + erff(v*0.70710678118654752f));
        size_t idx = (size_t)(rr + reg)*N + cc;
        if (OUT == 0)      ((float*)Cv)[idx] = v;
        else if (OUT == 1) ((float*)Cv)[idx] += v;
        else               ((ushort*)Cv)[idx] = f2bf(v);
      }
    }
  }
}

// ---- QKV / pool-KV GEMM, TM=64 tile (wave 32x64) with fused per-head LN; V direct-transposed ----
// POOL=0: N=1536 -> Qh/Kh bf16 [b,h,l,64] (LN, Q scaled), V -> VhT [b,h,64,LMAX] (2B scalar
//         stores; wave covers 64 consecutive l per dh row -> L2 write-combines). Tail l>=Lb
//         never written: 0xAA poison decodes to a FINITE bf16; masked P=0 gives 0 contribution.
// POOL=1: N=1024 -> KV fp32 [row][1024] (LN on K cols<512).
template<int POOL>
__global__ __launch_bounds__(256) void gemm_qkv_k(
    const ushort* __restrict__ A, const ushort* __restrict__ W,
    const float* __restrict__ gq, const float* __restrict__ gk,
    ushort* __restrict__ Qh, ushort* __restrict__ Kh, ushort* __restrict__ VhT,
    float* __restrict__ KV, int N) {
  const int K = DIM;
  __shared__ ushort As[64*64];
  __shared__ ushort Ws[128*64];
  int tid = threadIdx.x;
  int row0 = blockIdx.y*64, col0 = blockIdx.x*128;
  int lane = tid & 63, l15 = lane & 15, quad = lane >> 4;
  int wv = tid >> 6, wm = wv >> 1, wn = wv & 1;   // 2x2 waves, wave tile 32x64
  int sw = l15 & 7;
  int segA = (quad ^ sw) * 8, segB = segA ^ 32;
  const ushort *Ap[2], *Wp[4];
  #pragma unroll
  for (int j = 0; j < 2; ++j) {
    int blk = j*256 + tid;
    int r = blk >> 3, s = ((blk & 7) ^ (r & 7)) * 8;
    Ap[j] = A + (size_t)(row0 + r)*K + s;
  }
  #pragma unroll
  for (int j = 0; j < 4; ++j) {
    int blk = j*256 + tid;
    int r = blk >> 3, s = ((blk & 7) ^ (r & 7)) * 8;
    Wp[j] = W + (size_t)(col0 + r)*K + s;
  }
  floatx4 acc[2][4] = {};
  for (int k0 = 0; k0 < K; k0 += 64) {
    __syncthreads();
    #pragma unroll
    for (int j = 0; j < 2; ++j) GLOAD_LDS16(Ap[j] + k0, &As[(j*256+tid)*8]);
    #pragma unroll
    for (int j = 0; j < 4; ++j) GLOAD_LDS16(Wp[j] + k0, &Ws[(j*256+tid)*8]);
    __syncthreads();
    #pragma unroll
    for (int w = 0; w < 2; ++w) {
      int sg = w ? segB : segA;
      short8 af[2], bf[4];
      #pragma unroll
      for (int i = 0; i < 2; ++i) af[i] = *(const short8*)&As[(wm*32 + i*16 + l15)*64 + sg];
      #pragma unroll
      for (int j = 0; j < 4; ++j) bf[j] = *(const short8*)&Ws[(wn*64 + j*16 + l15)*64 + sg];
      #pragma unroll
      for (int i = 0; i < 2; ++i)
        #pragma unroll
        for (int j = 0; j < 4; ++j)
          acc[i][j] = __builtin_amdgcn_mfma_f32_16x16x32_bf16(af[i], bf[j], acc[i][j], 0, 0, 0);
    }
  }
  int unit = (col0 >> 6) + wn;
  bool needln = POOL ? (unit < 8) : (unit < 16);
  const float* gain = POOL ? gq : (unit < 8 ? gq : gk);
  #pragma unroll
  for (int i = 0; i < 2; ++i) {
    float s[4] = {0,0,0,0}, s2[4] = {0,0,0,0};
    if (needln) {
      #pragma unroll
      for (int j = 0; j < 4; ++j)
        #pragma unroll
        for (int reg = 0; reg < 4; ++reg) {
          float v = acc[i][j][reg];
          s[reg] += v; s2[reg] += v*v;
        }
      #pragma unroll
      for (int reg = 0; reg < 4; ++reg)
        #pragma unroll
        for (int off = 1; off < 16; off <<= 1) {
          s[reg]  += __shfl_xor(s[reg],  off);
          s2[reg] += __shfl_xor(s2[reg], off);
        }
    }
    #pragma unroll
    for (int reg = 0; reg < 4; ++reg) {
      int r = row0 + wm*32 + i*16 + quad*4 + reg;
      if (r >= MVALID) continue;
      float mu = s[reg]*(1.f/64.f);
      float rs = rsqrtf(fmaxf(s2[reg]*(1.f/64.f) - mu*mu, 0.f) + 1e-5f);
      int b = row2img(r), l = r - c_off[b];
      #pragma unroll
      for (int j = 0; j < 4; ++j) {
        int dh = j*16 + l15;
        float v = acc[i][j][reg];
        if (needln) v = (v - mu)*rs*gain[dh];
        if (POOL) {
          KV[(size_t)r*1024 + unit*64 + dh] = v;
        } else {
          int h = unit & 7;
          if (unit < 8) {
            Qh[((size_t)(b*8+h)*LMAXS + l)*64 + dh] = f2bf(v * QSCALE);
          } else if (unit < 16) {
            Kh[((size_t)(b*8+h)*LMAXS + l)*64 + dh] = f2bf(v);
          } else {
            VhT[((size_t)(b*8+h)*64 + dh)*LMAXS + l] = f2bf(v);  // fused transpose
          }
        }
      }
    }
  }
}

// ---- row LayerNorm: fp32 T -> bf16 XN ----
__global__ __launch_bounds__(256) void row_ln_bf_k(
    const float* __restrict__ T, const float* __restrict__ g, ushort* __restrict__ Y) {
  __shared__ float red[8];
  size_t base = (size_t)blockIdx.x * DIM;
  float v0 = T[base + threadIdx.x], v1 = T[base + threadIdx.x + 256];
  float s = v0 + v1, s2 = v0*v0 + v1*v1;
  reduce2_256(s, s2, red);
  float mu = s*(1.f/DIM), rs = rsqrtf(fmaxf(s2*(1.f/DIM) - mu*mu, 0.f) + 1e-5f);
  Y[base + threadIdx.x]       = f2bf((v0-mu)*rs*g[threadIdx.x]);
  Y[base + threadIdx.x + 256] = f2bf((v1-mu)*rs*g[threadIdx.x + 256]);
}

// ---- LN2 + bias + pos embed, packed, in place on fp32 T ----
__global__ __launch_bounds__(256) void ln2_pos_k(
    float* __restrict__ T, const float* __restrict__ g, const float* __restrict__ bb,
    const float* __restrict__ ph, const float* __restrict__ pw) {
  int r = blockIdx.x;
  float* x = T + (size_t)r * DIM;
  if (r >= MVALID) {
    for (int i = threadIdx.x; i < DIM; i += 256) x[i] = 0.f;
    return;
  }
  int b = row2img(r), l = r - c_off[b];
  __shared__ float red[8];
  int wgrid = c_w[b];
  int hi = l / wgrid, wi = l % wgrid;
  float s=0.f, s2=0.f;
  for (int i = threadIdx.x; i < DIM; i += 256) { float v = x[i]; s+=v; s2+=v*v; }
  reduce2_256(s, s2, red);
  float mu = s*(1.f/DIM), rs = rsqrtf(fmaxf(s2*(1.f/DIM)-mu*mu, 0.f)+1e-5f);
  for (int i = threadIdx.x; i < DIM; i += 256)
    x[i] = (x[i]-mu)*rs*g[i] + bb[i] + ph[hi*DIM+i] + pw[wi*DIM+i];
}

// ---- flash-decoding attention, phase 1: per (bh, qtile, key-slice of 512) ----
// PART slice layout: 4160 floats = O[64q][64d] then l[64q].
__global__ __launch_bounds__(256) void attn_part_k(
    const ushort* __restrict__ Qh, const ushort* __restrict__ Kh,
    const ushort* __restrict__ VhT, float* __restrict__ PART) {
  int bh = blockIdx.x, b = bh >> 3;
  int Lb = c_L[b];
  int qt = blockIdx.y, z = blockIdx.z;
  if (qt*64 >= Lb || z*512 >= Lb) return;
  __shared__ ushort Ks[64*64];
  __shared__ ushort Vt[64*64];
  __shared__ ushort Pb[4][16][68];
  int tid = threadIdx.x, wv = tid >> 6, lane = tid & 63;
  int quad = lane >> 4, l15 = lane & 15;
  int sw = l15 & 7;
  int segA = (quad ^ sw) * 8, segB = segA ^ 32;
  int q0 = qt*64 + wv*16;
  bool active = q0 < Lb;
  const ushort* qhb = Qh + (size_t)bh * LMAXS * DH;
  const ushort* khb = Kh + (size_t)bh * LMAXS * DH;
  const ushort* vtb = VhT + (size_t)bh * DH * LMAXS;
  short8 aq0 = {}, aq1 = {};
  if (active) {
    const ushort* qp = qhb + (size_t)(q0 + l15) * DH;
    aq0 = *(const short8*)(qp + quad*8);
    aq1 = *(const short8*)(qp + 32 + quad*8);
  }
  int blk0 = tid, blk1 = tid + 256;
  int kr0 = blk0 >> 3, s0 = ((blk0 & 7) ^ (kr0 & 7)) * 8;
  int kr1 = blk1 >> 3, s1 = ((blk1 & 7) ^ (kr1 & 7)) * 8;
  const ushort* kg0 = khb + kr0*DH + s0;
  const ushort* kg1 = khb + kr1*DH + s1;
  const ushort* vg0 = vtb + (size_t)kr0*LMAXS + s0;
  const ushort* vg1 = vtb + (size_t)kr1*LMAXS + s1;
  int kbeg = z*512, kend = min(kbeg + 512, Lb);
  float lsum[4] = {0.f,0.f,0.f,0.f};
  floatx4 o[4] = {};
  for (int kc = kbeg; kc < kend; kc += 64) {
    __syncthreads();
    GLOAD_LDS16(kg0 + kc*DH, &Ks[blk0*8]);
    GLOAD_LDS16(kg1 + kc*DH, &Ks[blk1*8]);
    GLOAD_LDS16(vg0 + kc,    &Vt[blk0*8]);
    GLOAD_LDS16(vg1 + kc,    &Vt[blk1*8]);
    __syncthreads();
    if (!active) continue;
    bool tail = (kc + 64 > Lb);
    #pragma unroll
    for (int kb = 0; kb < 4; ++kb) {
      int krow = (kb*16 + l15) * 64;
      floatx4 s = {};
      s = __builtin_amdgcn_mfma_f32_16x16x32_bf16(aq0, *(const short8*)&Ks[krow + segA], s, 0,0,0);
      s = __builtin_amdgcn_mfma_f32_16x16x32_bf16(aq1, *(const short8*)&Ks[krow + segB], s, 0,0,0);
      #pragma unroll
      for (int reg = 0; reg < 4; ++reg) {
        float x = s[reg];
        if (tail && (kc + kb*16 + l15 >= Lb)) x = -1e9f;
        float p = __builtin_amdgcn_exp2f(x);
        lsum[reg] += p;
        Pb[wv][quad*4+reg][kb*16+l15] = f2bf(p);
      }
    }
    short8 a0 = *(const short8*)&Pb[wv][l15][quad*8];
    short8 a1 = *(const short8*)&Pb[wv][l15][32+quad*8];
    #pragma unroll
    for (int nb = 0; nb < 4; ++nb) {
      int vrow = (nb*16 + l15) * 64;
      o[nb] = __builtin_amdgcn_mfma_f32_16x16x32_bf16(a0, *(const short8*)&Vt[vrow + segA], o[nb], 0,0,0);
      o[nb] = __builtin_amdgcn_mfma_f32_16x16x32_bf16(a1, *(const short8*)&Vt[vrow + segB], o[nb], 0,0,0);
    }
  }
  if (active) {
    size_t sb = ((size_t)(bh*16 + qt)*2 + z) * 4160;
    #pragma unroll
    for (int reg = 0; reg < 4; ++reg) {
      float s = lsum[reg];
      s += __shfl_xor(s,1); s += __shfl_xor(s,2); s += __shfl_xor(s,4); s += __shfl_xor(s,8);
      if (l15 == 0) PART[sb + 4096 + wv*16 + quad*4 + reg] = s;
    }
    int rq = wv*16 + quad*4;
    #pragma unroll
    for (int nb = 0; nb < 4; ++nb)
      #pragma unroll
      for (int reg = 0; reg < 4; ++reg)
        PART[sb + (size_t)(rq + reg)*64 + nb*16 + l15] = o[nb][reg];
  }
}

// ---- flash-decoding attention, phase 2: combine slices, write bf16 ATTO ----
__global__ __launch_bounds__(256) void attn_comb_k(
    const float* __restrict__ PART, ushort* __restrict__ O) {
  int bh = blockIdx.x, b = bh >> 3, h = bh & 7;
  int Lb = c_L[b];
  int qt = blockIdx.y;
  if (qt*64 >= Lb) return;
  int nsl = (Lb + 511) >> 9;
  int t = threadIdx.x;
  int q = t >> 2, dj = (t & 3) * 16;
  int qq = qt*64 + q;
  if (qq >= Lb) return;
  size_t base = (size_t)(bh*16 + qt)*2*4160;
  float o[16] = {};
  float l = 0.f;
  for (int zz = 0; zz < nsl; ++zz) {
    const float* sp = PART + base + (size_t)zz*4160;
    #pragma unroll
    for (int i = 0; i < 16; i += 4) {
      float4 v = *(const float4*)&sp[q*64 + dj + i];
      o[i] += v.x; o[i+1] += v.y; o[i+2] += v.z; o[i+3] += v.w;
    }
    l += sp[4096 + q];
  }
  float inv = 1.f / l;
  short8 r0, r1;
  #pragma unroll
  for (int i = 0; i < 8; ++i) r0[i] = (short)f2bf(o[i]*inv);
  #pragma unroll
  for (int i = 0; i < 8; ++i) r1[i] = (short)f2bf(o[8+i]*inv);
  ushort* dst = O + (size_t)(c_off[b]+qq)*DIM + h*DH + dj;
  *(short8*)dst     = r0;
  *(short8*)(dst+8) = r1;
}

// ---- pool query prep A: qp = LN(pool_q) @ pool_wq^T, column-parallel (8 blocks) ----
__global__ __launch_bounds__(256) void pool_prep_a_k(
    const float* __restrict__ pq, const float* __restrict__ pln,
    const float* __restrict__ pwq, float* __restrict__ qp) {
  __shared__ float qln[DIM];
  __shared__ float red[8];
  int tid = threadIdx.x;
  float s=0.f, s2=0.f;
  for (int i=tid;i<DIM;i+=256){ float v=pq[i]; s+=v; s2+=v*v; }
  reduce2_256(s, s2, red);
  float mu=s*(1.f/DIM), rs=rsqrtf(fmaxf(s2*(1.f/DIM)-mu*mu,0.f)+1e-5f);
  for (int i=tid;i<DIM;i+=256) qln[i]=(pq[i]-mu)*rs*pln[i];
  __syncthreads();
  int n = blockIdx.x*64 + (tid>>2);
  int kq = (tid&3)*128;
  const float4* wr = (const float4*)(pwq + (size_t)n*DIM + kq);
  float a=0.f;
  #pragma unroll
  for (int k=0;k<32;++k) {
    float4 w4 = wr[k];
    float4 q4 = *(const float4*)&qln[kq + k*4];
    a += w4.x*q4.x + w4.y*q4.y + w4.z*q4.z + w4.w*q4.w;
  }
  a += __shfl_xor(a,1); a += __shfl_xor(a,2);
  if ((tid&3)==0) qp[n]=a;
}

// ---- pool query prep B: per-head LN on qp -> qpool ----
__global__ __launch_bounds__(512) void pool_prep_b_k(
    const float* __restrict__ qp, const float* __restrict__ pqn, float* __restrict__ qpool) {
  int h = threadIdx.x >> 6, lane = threadIdx.x & 63;
  float v = qp[h*64 + lane];
  float s = v, s2 = v*v;
  #pragma unroll
  for (int off=32; off; off>>=1) { s += __shfl_xor(s,off); s2 += __shfl_xor(s2,off); }
  float mu = s*(1.f/64), rs = rsqrtf(fmaxf(s2*(1.f/64)-mu*mu, 0.f)+1e-5f);
  qpool[h*64+lane] = (v-mu)*rs*pqn[lane];
}

// ---- pooling cross-attention, phase 1 ----
__global__ __launch_bounds__(256) void pool_attn_part_k(
    const float* __restrict__ qpool, const float* __restrict__ KV,
    float* __restrict__ PARTP) {
  __shared__ float qh[DH];
  __shared__ float ps[256];
  __shared__ float op[4][DH];
  __shared__ float red[8];
  int bh = blockIdx.x, c = blockIdx.y;
  int b = bh>>3, h = bh&7;
  int Lb = c_L[b];
  int tid = threadIdx.x;
  if (tid < DH) qh[tid] = qpool[h*DH + tid];
  __syncthreads();
  int kk = c*256 + tid;
  float p = 0.f;
  if (kk < Lb) {
    const float4* kp = (const float4*)(KV + (size_t)(c_off[b]+kk)*1024 + h*DH);
    float a = 0.f;
    #pragma unroll
    for (int dd=0; dd<16; ++dd) {
      float4 kv = kp[dd];
      a += kv.x*qh[dd*4] + kv.y*qh[dd*4+1] + kv.z*qh[dd*4+2] + kv.w*qh[dd*4+3];
    }
    p = __expf(a*0.125f);
  }
  ps[tid] = p;
  float s = p, s2 = 0.f;
  reduce2_256(s, s2, red);
  int wvv = tid >> 6, lane = tid & 63;
  float o = 0.f;
  int kb = c*256 + wvv*64;
  const float* vb = KV + (size_t)c_off[b]*1024 + 512 + h*DH + lane;
  for (int j = 0; j < 64; ++j) {
    int key = kb + j;
    if (key < Lb) o += ps[wvv*64+j] * vb[(size_t)key*1024];
  }
  op[wvv][lane] = o;
  __syncthreads();
  if (tid < DH)
    PARTP[((size_t)bh*4 + c)*66 + tid] = op[0][tid]+op[1][tid]+op[2][tid]+op[3][tid];
  if (tid == 64)
    PARTP[((size_t)bh*4 + c)*66 + 64] = s;
}

// ---- pooling cross-attention, phase 2 ----
__global__ __launch_bounds__(64) void pool_attn_comb_k(
    const float* __restrict__ PARTP, float* __restrict__ O) {
  int bh = blockIdx.x, b = bh>>3, h = bh&7, d = threadIdx.x;
  float o = 0.f, sum = 0.f;
  #pragma unroll
  for (int c = 0; c < 4; ++c) {
    o   += PARTP[((size_t)bh*4 + c)*66 + d];
    sum += PARTP[((size_t)bh*4 + c)*66 + 64];
  }
  O[(size_t)b*DIM + h*DH + d] = o / sum;
}

// ---- tiny projection, column-split ----
__global__ __launch_bounds__(256) void proj512_k(
    const float* __restrict__ X, const float* __restrict__ W, float* __restrict__ Y) {
  __shared__ float xr[DIM];
  int b = blockIdx.x, tid = threadIdx.x;
  for (int i=tid;i<DIM;i+=256) xr[i] = X[(size_t)b*DIM+i];
  __syncthreads();
  if (tid < 128) {
    int n = blockIdx.y*128 + tid;
    const float4* wr = (const float4*)(W + (size_t)n*DIM);
    float a=0.f;
    for (int k=0;k<DIM/4;++k) { float4 w4 = wr[k]; a += w4.x*xr[k*4]+w4.y*xr[k*4+1]+w4.z*xr[k*4+2]+w4.w*xr[k*4+3]; }
    Y[(size_t)b*DIM+n]=a;
  }
}

// ---- final LN + classifier head, column-split ----
__global__ __launch_bounds__(256) void head_out_k(
    const float* __restrict__ X, const float* __restrict__ g,
    const float* __restrict__ W, float* __restrict__ out) {
  __shared__ float xr[DIM];
  __shared__ float red[8];
  int b = blockIdx.x, tid = threadIdx.x;
  float s=0.f, s2=0.f;
  for (int i=tid;i<DIM;i+=256){ float v=X[(size_t)b*DIM+i]; s+=v; s2+=v*v; }
  reduce2_256(s, s2, red);
  float mu=s*(1.f/DIM), rs=rsqrtf(fmaxf(s2*(1.f/DIM)-mu*mu,0.f)+1e-5f);
  for (int i=tid;i<DIM;i+=256) xr[i]=(X[(size_t)b*DIM+i]-mu)*rs*g[i];
  __syncthreads();
  if (tid < 125) {
    int n = blockIdx.y*125 + tid;
    const float4* wr = (const float4*)(W + (size_t)n*DIM);
    float a=0.f;
    for (int k=0;k<DIM/4;++k){ float4 w4=wr[k]; a += w4.x*xr[k*4]+w4.y*xr[k*4+1]+w4.z*xr[k*4+2]+w4.w*xr[k*4+3]; }
    out[(size_t)b*NC+n]=a;
  }
}

extern "C" void kernel_launch(void* const* d_in, const int* in_sizes, int n_in,
                              void* d_out, int out_size, void* d_ws, size_t ws_size,
                              hipStream_t stream) {
  const float* images  = (const float*)d_in[0];
  const float* pe_ln1_w= (const float*)d_in[1];
  const float* pe_ln1_b= (const float*)d_in[2];
  const float* pe_w    = (const float*)d_in[3];
  const float* pe_b    = (const float*)d_in[4];
  const float* pe_ln2_w= (const float*)d_in[5];
  const float* pe_ln2_b= (const float*)d_in[6];
  const float* pos_h   = (const float*)d_in[7];
  const float* pos_w   = (const float*)d_in[8];
  const float* attn_ln = (const float*)d_in[9];
  const float* wq      = (const float*)d_in[10];
  const float* wk      = (const float*)d_in[11];
  const float* wvp     = (const float*)d_in[12];
  const float* qn      = (const float*)d_in[13];
  const float* kn      = (const float*)d_in[14];
  const float* wo      = (const float*)d_in[15];
  const float* ff_ln   = (const float*)d_in[16];
  const float* ff_w1   = (const float*)d_in[17];
  const float* ff_b1   = (const float*)d_in[18];
  const float* ff_w2   = (const float*)d_in[19];
  const float* ff_b2   = (const float*)d_in[20];
  const float* final_ln= (const float*)d_in[21];
  const float* pool_q  = (const float*)d_in[22];
  const float* pool_ln = (const float*)d_in[23];
  const float* pool_wq = (const float*)d_in[24];
  const float* pool_wk = (const float*)d_in[25];
  const float* pool_wv = (const float*)d_in[26];
  const float* pool_qn = (const float*)d_in[27];
  const float* pool_kn = (const float*)d_in[28];
  const float* pool_wo = (const float*)d_in[29];
  const float* head_ln = (const float*)d_in[30];
  const float* head_w  = (const float*)d_in[31];
  (void)ws_size; (void)in_sizes; (void)n_in; (void)out_size;

  char* p = (char*)d_ws;
  ushort* WQKVc = (ushort*)p; p += (size_t)6*1536*512*2;
  ushort* WOc   = (ushort*)p; p += (size_t)6*512*512*2;
  ushort* W1c   = (ushort*)p; p += (size_t)6*2048*512*2;
  ushort* W2c   = (ushort*)p; p += (size_t)6*512*2048*2;
  ushort* PEWc  = (ushort*)p; p += (size_t)512*768*2;
  ushort* PKVc  = (ushort*)p; p += (size_t)1024*512*2;
  float*  T     = (float*)p;  p += (size_t)MPACK*DIM*4;
  ushort* XN    = (ushort*)p; p += (size_t)MPACK*DIM*2;
  ushort* Qh    = (ushort*)p; p += (size_t)64*LMAXS*DH*2;
  ushort* Kh    = (ushort*)p; p += (size_t)64*LMAXS*DH*2;
  ushort* VhT   = (ushort*)p; p += (size_t)64*64*LMAXS*2;
  ushort* FFH   = (ushort*)p; p += (size_t)MPACK*MLP*2;   // TOK/ATTO alias inside
  ushort* TOK   = FFH;
  ushort* ATTO  = FFH;
  float*  PART  = (float*)p;  p += (size_t)64*16*2*4160*4; // 34.1 MB
  float*  KVb   = (float*)p;  p += (size_t)MPACK*1024*4;   // 22.0 MB
  float*  QP    = (float*)p;  p += DIM*4;
  float*  QPOOL = (float*)p;  p += DIM*4;
  float*  POOLO = (float*)p;  p += NB*DIM*4;
  float*  POOLED= (float*)p;  p += NB*DIM*4;
  float*  PARTP = (float*)p;  p += (size_t)64*4*66*4;

  // ---- fused weight conversion (single dispatch, same work every call) ----
  cvt_all_k<<<19328, 256, 0, stream>>>(wq, wk, wvp, wo, ff_w1, ff_w2, pe_w,
                                       pool_wk, pool_wv,
                                       WQKVc, WOc, W1c, W2c, PEWc, PKVc);

  // ---- patch embed (packed) ----
  pack_ln1_k<<<MPACK, 256, 0, stream>>>(images, pe_ln1_w, pe_ln1_b, TOK);
  gemm_t<64,128,64,32,0,0><<<dim3(4, MPACK/64), 256, 0, stream>>>(TOK, PEWc, pe_b, T, MPACK, DIM, PDIM);
  ln2_pos_k<<<MPACK, 256, 0, stream>>>(T, pe_ln2_w, pe_ln2_b, pos_h, pos_w);

  // ---- transformer layers ----
  for (int l = 0; l < DEPTH; ++l) {
    row_ln_bf_k<<<MPACK, 256, 0, stream>>>(T, attn_ln + l*DIM, XN);
    gemm_qkv_k<0><<<dim3(12, MPACK/64), 256, 0, stream>>>(
        XN, WQKVc + (size_t)l*1536*512, qn + l*DH, kn + l*DH, Qh, Kh, VhT, nullptr, 1536);
    attn_part_k<<<dim3(64, 16, 2), 256, 0, stream>>>(Qh, Kh, VhT, PART);
    attn_comb_k<<<dim3(64, 16), 256, 0, stream>>>(PART, ATTO);
    gemm_t<64,64,32,32,0,1><<<dim3(8, MPACK/64), 256, 0, stream>>>(ATTO, WOc + (size_t)l*512*512, nullptr, T, MPACK, DIM, DIM);
    row_ln_bf_k<<<MPACK, 256, 0, stream>>>(T, ff_ln + l*DIM, XN);
    gemm_t<64,128,64,32,1,2><<<dim3(16, MPACK/64), 256, 0, stream>>>(XN, W1c + (size_t)l*MLP*DIM, ff_b1 + l*MLP, FFH, MPACK, MLP, DIM);
    gemm_t<64,64,32,32,0,1><<<dim3(8, MPACK/64), 256, 0, stream>>>(FFH, W2c + (size_t)l*DIM*MLP, ff_b2 + l*DIM, T, MPACK, DIM, MLP);
  }

  // ---- pooling head ----
  row_ln_bf_k<<<MPACK, 256, 0, stream>>>(T, final_ln, XN);
  pool_prep_a_k<<<8, 256, 0, stream>>>(pool_q, pool_ln, pool_wq, QP);
  pool_prep_b_k<<<1, 512, 0, stream>>>(QP, pool_qn, QPOOL);
  gemm_qkv_k<1><<<dim3(8, MPACK/64), 256, 0, stream>>>(
      XN, PKVc, pool_kn, nullptr, nullptr, nullptr, nullptr, KVb, 1024);
  pool_attn_part_k<<<dim3(64, 4), 256, 0, stream>>>(QPOOL, KVb, PARTP);
  pool_attn_comb_k<<<64, 64, 0, stream>>>(PARTP, POOLO);
  proj512_k<<<dim3(8, 4), 256, 0, stream>>>(POOLO, pool_wo, POOLED);
  head_out_k<<<dim3(8, 8), 256, 0, stream>>>(POOLED, head_ln, head_w, (float*)d_out);
}